// Round 5
// baseline (400.181 us; speedup 1.0000x reference)
//
#include <hip/hip_runtime.h>

// Problem constants (fixed by the reference):
//   x        [B=4096, D=16384] fp32
//   hashProj [D=16384, E=1024] fp32, exactly one nonzero (+-1) per row
//   out      [B=4096, E=1024]  fp32 = x @ hashProj
#define DIM_D 16384
#define DIM_E 1024
#define DIM_B 4096
#define HALF_D 8192
#define HALF_CAP 48   // per-half bucket cap; counts ~Poisson(8), P(>48) < 1e-20

// ---------------------------------------------------------------------------
// Architecture: ELL gather, now split by feature half so each gather block
// can pipeline {stage hi-half || compute lo-half} with a counted vmcnt
// (a __syncthreads-drained structure cannot overlap within a block).
//   K1: scan hashProj rows; founder lane claims a slot in bucket e of
//       ELL_lo (j<8192) or ELL_hi (j>=8192) via atomicAdd and writes a
//       ushort entry ((j&8191) | neg<<15). Half choice is wave-uniform.
//   K2: one 1024-thread block per batch row.
//       issue lo-DMA (2x16B/thread) | issue hi-DMA | preamble VALU under
//       the in-flight loads | s_waitcnt vmcnt(2) (lo retired, hi still
//       flying) + raw s_barrier | compute lo while hi streams |
//       __syncthreads (cheap drain) | compute hi | store row.
//       sched_barrier(0) fences pin VMEM issue order so vmcnt(2) provably
//       covers both lo-DMAs (>=2 younger VMEM ops follow them).
// Entries beyond a bucket's own count are masked to +0.0f in VALU, so the
// ELLs need no pad prefill (poisoned garbage decodes in-range, then zeroed).
// LDS-atomic scatter (round 2) measured 3.25 cyc/lane-op -- still avoided.
// Workspace: ell_lo 96K + ell_hi 96K + cursors 8K; only cursors memset.
// ---------------------------------------------------------------------------

__global__ __launch_bounds__(256) void hash_extract_fill(
    const float* __restrict__ hashProj,
    int* __restrict__ cursor_lo, int* __restrict__ cursor_hi,
    unsigned short* __restrict__ ell_lo, unsigned short* __restrict__ ell_hi) {
  const int wave = threadIdx.x >> 6;
  const int lane = threadIdx.x & 63;
  const int row = blockIdx.x * 4 + wave;   // 4096 blocks x 4 waves = 16384 rows
  const float4* rp = (const float4*)(hashProj + (size_t)row * DIM_E);
  int found_e = -1;
  float found_s = 0.f;
#pragma unroll
  for (int k = 0; k < 4; ++k) {
    const int p = lane + 64 * k;           // float4 position within row
    float4 v = rp[p];
    const int base = p * 4;
    if (v.x != 0.f) { found_e = base + 0; found_s = v.x; }
    if (v.y != 0.f) { found_e = base + 1; found_s = v.y; }
    if (v.z != 0.f) { found_e = base + 2; found_s = v.z; }
    if (v.w != 0.f) { found_e = base + 3; found_s = v.w; }
  }
  if (found_e >= 0) {
    const bool hi = row >= HALF_D;         // wave-uniform
    int* cur = hi ? cursor_hi : cursor_lo;
    unsigned short* ell = hi ? ell_hi : ell_lo;
    const int slot = atomicAdd(&cur[found_e], 1);   // cursor starts at 0
    if (slot < HALF_CAP) {
      // group g = slot>>2 lives at ushort4 index g*1024+e (lane-consecutive
      // e -> coalesced 8B loads in the gather).
      ell[(slot >> 2) * (4 * DIM_E) + 4 * found_e + (slot & 3)] =
          (unsigned short)((row & (HALF_D - 1)) |
                           ((found_s < 0.f) ? 0x8000 : 0));
    }
  }
}

// Decode entry q (k-th slot of a group whose remaining count is r) against
// a HALF_D-sized LDS window:
//   valid (k < r): +-xs[j]  (sign bit 15 -> fp32 sign XOR, exact)
//   invalid      : +0.0f    (garbage entries decode in-range, then masked)
__device__ __forceinline__ float ell_val(const float* xs, int q, int k, int r) {
  float v = xs[q & (HALF_D - 1)];
  int iv = __float_as_int(v);
  iv ^= (q & 0x8000) << 16;        // bit15 -> fp32 sign bit
  iv &= (k - r) >> 31;             // k < r ? ~0 : 0
  return __int_as_float(iv);
}

__global__ __launch_bounds__(1024) void hash_gather(
    const float* __restrict__ x,
    const int* __restrict__ cursor_lo, const int* __restrict__ cursor_hi,
    const unsigned short* __restrict__ ell_lo,
    const unsigned short* __restrict__ ell_hi,
    float* __restrict__ out) {
  __shared__ float xs[DIM_D];              // [0,8192) = lo, [8192,16384) = hi
  const int t = threadIdx.x;
  const int b = blockIdx.x;
  const float* xrow = x + (size_t)b * DIM_D;
  const ushort4* eplo = (const ushort4*)ell_lo;
  const ushort4* ephi = (const ushort4*)ell_hi;

  // --- VMEM issue order (pinned by sched_barrier fences) ---
  // [cursors + lo group-0 prefetch] [2 lo-DMA] [2 hi-DMA, hi group-0]
  int c_lo = cursor_lo[t];
  int c_hi = cursor_hi[t];
  ushort4 qlo = eplo[t];
  __builtin_amdgcn_sched_barrier(0);
#pragma unroll
  for (int i = 0; i < 2; ++i) {            // lo half: 32 KiB
    const int p = (t + i * 1024) * 4;
    __builtin_amdgcn_global_load_lds(
        (const __attribute__((address_space(1))) void*)(xrow + p),
        (__attribute__((address_space(3))) void*)(xs + p),
        16, 0, 0);
  }
  __builtin_amdgcn_sched_barrier(0);
#pragma unroll
  for (int i = 2; i < 4; ++i) {            // hi half: 32 KiB
    const int p = (t + i * 1024) * 4;
    __builtin_amdgcn_global_load_lds(
        (const __attribute__((address_space(1))) void*)(xrow + p),
        (__attribute__((address_space(3))) void*)(xs + p),
        16, 0, 0);
  }
  ushort4 qhi = ephi[t];
  __builtin_amdgcn_sched_barrier(0);

  // Preamble VALU runs under the in-flight DMAs (compiler waits only the
  // minimal vmcnt needed to consume the cursor values).
  if (c_lo > HALF_CAP) c_lo = HALF_CAP;
  if (c_hi > HALF_CAP) c_hi = HALF_CAP;
  int m_lo = c_lo, m_hi = c_hi;
#pragma unroll
  for (int off = 32; off >= 1; off >>= 1) {
    m_lo = max(m_lo, __shfl_xor(m_lo, off));
    m_hi = max(m_hi, __shfl_xor(m_hi, off));
  }
  const int G_lo = (m_lo + 3) >> 2;        // wave-uniform group counts
  const int G_hi = (m_hi + 3) >> 2;

  // lo-DMAs have >=2 younger VMEM ops -> vmcnt(2) retires them while both
  // hi-DMAs keep streaming across the barrier (T4: never drain to 0 here).
  asm volatile("s_waitcnt vmcnt(2)" ::: "memory");
  __builtin_amdgcn_s_barrier();
  __builtin_amdgcn_sched_barrier(0);

  // --- compute lo half while hi half streams from HBM ---
  float s0 = 0.f, s1 = 0.f, s2 = 0.f, s3 = 0.f;
  {
    ushort4 q = qlo;
    int r = c_lo;
    for (int g = 1; g < G_lo; ++g) {
      ushort4 qn = eplo[g * DIM_E + t];
      s0 += ell_val(xs, q.x, 0, r);
      s1 += ell_val(xs, q.y, 1, r);
      s2 += ell_val(xs, q.z, 2, r);
      s3 += ell_val(xs, q.w, 3, r);
      q = qn;
      r = c_lo - g * 4;
    }
    s0 += ell_val(xs, q.x, 0, r);
    s1 += ell_val(xs, q.y, 1, r);
    s2 += ell_val(xs, q.z, 2, r);
    s3 += ell_val(xs, q.w, 3, r);
  }

  __syncthreads();                         // hi-DMAs retired during lo compute

  // --- compute hi half ---
  {
    const float* xh = xs + HALF_D;
    ushort4 q = qhi;
    int r = c_hi;
    for (int g = 1; g < G_hi; ++g) {
      ushort4 qn = ephi[g * DIM_E + t];
      s0 += ell_val(xh, q.x, 0, r);
      s1 += ell_val(xh, q.y, 1, r);
      s2 += ell_val(xh, q.z, 2, r);
      s3 += ell_val(xh, q.w, 3, r);
      q = qn;
      r = c_hi - g * 4;
    }
    s0 += ell_val(xh, q.x, 0, r);
    s1 += ell_val(xh, q.y, 1, r);
    s2 += ell_val(xh, q.z, 2, r);
    s3 += ell_val(xh, q.w, 3, r);
  }

  out[(size_t)b * DIM_E + t] = (s0 + s1) + (s2 + s3);
}

extern "C" void kernel_launch(void* const* d_in, const int* in_sizes, int n_in,
                              void* d_out, int out_size, void* d_ws, size_t ws_size,
                              hipStream_t stream) {
  const float* x = (const float*)d_in[0];
  const float* hashProj = (const float*)d_in[1];
  float* out = (float*)d_out;

  // Workspace: ell_lo 96 KiB | ell_hi 96 KiB | cursor_lo 4 KiB | cursor_hi 4 KiB
  char* ws = (char*)d_ws;
  const size_t ell_bytes = (size_t)(HALF_CAP / 4) * 4 * DIM_E * sizeof(unsigned short);
  unsigned short* ell_lo = (unsigned short*)ws;
  unsigned short* ell_hi = (unsigned short*)(ws + ell_bytes);
  int* cursor_lo = (int*)(ws + 2 * ell_bytes);
  int* cursor_hi = cursor_lo + DIM_E;

  hipMemsetAsync(cursor_lo, 0, 2 * DIM_E * sizeof(int), stream);
  hash_extract_fill<<<DIM_D / 4, 256, 0, stream>>>(hashProj, cursor_lo,
                                                   cursor_hi, ell_lo, ell_hi);
  hash_gather<<<DIM_B, 1024, 0, stream>>>(x, cursor_lo, cursor_hi, ell_lo,
                                          ell_hi, out);
}

// Round 6
// 396.421 us; speedup vs baseline: 1.0095x; 1.0095x over previous
//
#include <hip/hip_runtime.h>

// Problem constants (fixed by the reference):
//   x        [B=4096, D=16384] fp32
//   hashProj [D=16384, E=1024] fp32, exactly one nonzero (+-1) per row
//   out      [B=4096, E=1024]  fp32 = x @ hashProj
#define DIM_D 16384
#define DIM_E 1024
#define DIM_B 4096
#define ELL_CAP 64   // bucket capacity; counts ~Poisson(16), P(>64) ~ 1e-50

// ---------------------------------------------------------------------------
// Architecture (ELL gather -- best measured structure, 395.9 us):
//   K1: scan hashProj rows (coalesced float4), founder lane claims a slot in
//       its bucket via atomicAdd(cursor) and writes a ushort entry
//       (j | neg<<15) into the transposed ELL (128 KiB, L2-resident).
//   K2: one 1024-thread block per batch row.
//       - Stage the x row into LDS via 4x width-16 global_load_lds per
//         thread (async DMA, no VGPR round-trip; lane-linear dest).
//       - While the DMA is in flight: read own bucket count, wave-max shuffle
//         for a uniform trip count, prefetch ELL group 0.
//       - __syncthreads() then the gather loop: coalesced 8B ELL loads, 4
//         independent ds_read chains, entries beyond the bucket's own count
//         masked to +0.0f in VALU (no pad prefill needed -- poisoned garbage
//         decodes in-range, then zeroed).
// Evidence from this session:
//   - LDS-atomic scatter: 3.25 cyc/lane-op serialization (round 2) - avoided.
//   - Intra-block stage/compute pipelining (counted vmcnt, split ELL):
//     neutral-to-negative (rounds 4/5) -- gather is HBM-stream-pinned via
//     2-blocks/CU co-residence; composite floor = 2x1GiB harness fills
//     (~319us) + 336 MiB mandatory traffic (~50us) + boundaries.
// Workspace: ell 128 KiB (ushort) + cursor 4 KiB; only cursor is memset.
// ---------------------------------------------------------------------------

__global__ __launch_bounds__(256) void hash_extract_fill(
    const float* __restrict__ hashProj,
    int* __restrict__ cursor,
    unsigned short* __restrict__ ell) {
  const int wave = threadIdx.x >> 6;
  const int lane = threadIdx.x & 63;
  const int row = blockIdx.x * 4 + wave;   // 4096 blocks x 4 waves = 16384 rows
  const float4* rp = (const float4*)(hashProj + (size_t)row * DIM_E);
  int found_e = -1;
  float found_s = 0.f;
#pragma unroll
  for (int k = 0; k < 4; ++k) {
    const int p = lane + 64 * k;           // float4 position within row
    float4 v = rp[p];
    const int base = p * 4;
    if (v.x != 0.f) { found_e = base + 0; found_s = v.x; }
    if (v.y != 0.f) { found_e = base + 1; found_s = v.y; }
    if (v.z != 0.f) { found_e = base + 2; found_s = v.z; }
    if (v.w != 0.f) { found_e = base + 3; found_s = v.w; }
  }
  if (found_e >= 0) {
    const int slot = atomicAdd(&cursor[found_e], 1);   // cursor starts at 0
    if (slot < ELL_CAP) {
      // group g = slot>>2 lives at ushort4 index g*1024+e (lane-consecutive
      // e -> coalesced 8B loads in the gather).
      ell[(slot >> 2) * (4 * DIM_E) + 4 * found_e + (slot & 3)] =
          (unsigned short)(row | ((found_s < 0.f) ? 0x8000 : 0));
    }
  }
}

// Decode entry q (k-th slot of a group whose remaining count is r):
//   valid (k < r): +-xs[j]  (sign bit 15 -> fp32 sign XOR, exact)
//   invalid      : +0.0f    (garbage entries decode in-range, then masked)
__device__ __forceinline__ float ell_val(const float* xs, int q, int k, int r) {
  float v = xs[q & (DIM_D - 1)];
  int iv = __float_as_int(v);
  iv ^= (q & 0x8000) << 16;        // bit15 -> fp32 sign bit
  iv &= (k - r) >> 31;             // k < r ? ~0 : 0
  return __int_as_float(iv);
}

__global__ __launch_bounds__(1024) void hash_gather(
    const float* __restrict__ x,
    const int* __restrict__ cursor,
    const unsigned short* __restrict__ ell,
    float* __restrict__ out) {
  __shared__ float xs[DIM_D];
  const int t = threadIdx.x;
  const int b = blockIdx.x;
  const float* xrow = x + (size_t)b * DIM_D;

  // Async stage: 4 x 16B DMA per thread, lane-linear LDS destination
  // (wave-uniform base + lane*16 -- the global_load_lds constraint).
#pragma unroll
  for (int i = 0; i < 4; ++i) {
    const int p = (t + i * 1024) * 4;      // float index, 16B-aligned
    __builtin_amdgcn_global_load_lds(
        (const __attribute__((address_space(1))) void*)(xrow + p),
        (__attribute__((address_space(3))) void*)(xs + p),
        16, 0, 0);
  }

  // Overlapped with the in-flight DMA: bucket count, wave-uniform trip
  // count, group-0 ELL prefetch.
  int c = cursor[t];
  if (c > ELL_CAP) c = ELL_CAP;
  int m = c;
#pragma unroll
  for (int off = 32; off >= 1; off >>= 1)
    m = max(m, __shfl_xor(m, off));
  const int G = (m + 3) >> 2;              // wave-uniform group count

  const ushort4* ep = (const ushort4*)ell;
  ushort4 q = ep[t];                       // prefetch group 0 (L2-resident)

  __syncthreads();                         // implicit vmcnt(0): DMA complete

  float s0 = 0.f, s1 = 0.f, s2 = 0.f, s3 = 0.f;
  int r = c;
  for (int g = 1; g < G; ++g) {
    ushort4 qn = ep[g * DIM_E + t];        // prefetch next group
    s0 += ell_val(xs, q.x, 0, r);
    s1 += ell_val(xs, q.y, 1, r);
    s2 += ell_val(xs, q.z, 2, r);
    s3 += ell_val(xs, q.w, 3, r);
    q = qn;
    r = c - g * 4;
  }
  s0 += ell_val(xs, q.x, 0, r);
  s1 += ell_val(xs, q.y, 1, r);
  s2 += ell_val(xs, q.z, 2, r);
  s3 += ell_val(xs, q.w, 3, r);
  out[(size_t)b * DIM_E + t] = (s0 + s1) + (s2 + s3);
}

extern "C" void kernel_launch(void* const* d_in, const int* in_sizes, int n_in,
                              void* d_out, int out_size, void* d_ws, size_t ws_size,
                              hipStream_t stream) {
  const float* x = (const float*)d_in[0];
  const float* hashProj = (const float*)d_in[1];
  float* out = (float*)d_out;

  char* ws = (char*)d_ws;
  unsigned short* ell = (unsigned short*)ws;              // 128 KiB
  int* cursor = (int*)(ws + (size_t)ELL_CAP * DIM_E * 2); // 4 KiB

  hipMemsetAsync(cursor, 0, DIM_E * sizeof(int), stream); // only cursors
  hash_extract_fill<<<DIM_D / 4, 256, 0, stream>>>(hashProj, cursor, ell);
  hash_gather<<<DIM_B, 1024, 0, stream>>>(x, cursor, ell, out);
}